// Round 7
// baseline (142.292 us; speedup 1.0000x reference)
//
#include <hip/hip_runtime.h>
#include <hip/hip_bf16.h>
#include <math.h>
#include <stdint.h>

#define NB 4
#define NQ 100
#define NCLS 81
#define NT 20
#define NHW 65536

typedef __attribute__((ext_vector_type(8))) short bf16x8;
typedef __attribute__((ext_vector_type(16))) float f32x16;

__device__ inline short to_bf16(float f) {
    __hip_bfloat16 h = __float2bfloat16(f);   // RNE; pairs fuse to v_cvt_pk_bf16_f32
    return __builtin_bit_cast(short, h);
}

// v_exp_f32 / v_log_f32 are base-2 on gfx950
__device__ inline float fast_exp2(float x) { return __builtin_amdgcn_exp2f(x); }
__device__ inline float fast_log2(float x) { return __builtin_amdgcn_logf(x); }

// ---------------------------------------------------------------------------
// Kernel 0: zero the Stm integer accumulator (ws is poisoned, not re-poisoned)
// ---------------------------------------------------------------------------
__global__ void k_init(int* __restrict__ StmI) {
    if (threadIdx.x < NB * NT) StmI[threadIdx.x] = 0;
}

// ---------------------------------------------------------------------------
// Kernel 1: fused main pass. One block per (b, chunk of CPX pixels).
//  phase A: threads 0..CPX/2-1 gather tgt (nearest 2x downsample) -> 20-bit
//           pixel words in LDS; ballot-popcount for Stm (int atomics).
//  phase B: build MFMA B-fragments (bf16 0/1; col 20 = all-ones -> Ssig free)
//  phase C: 4 waves x 32-q rows: sigmoid/softplus VALU + two 32x32x16 bf16
//           MFMAs per K-step (x-GEMM -> A, sig-GEMM -> D), split-K partials.
// ---------------------------------------------------------------------------
template<int SC>
__global__ void __launch_bounds__(256)
k_main(const float* __restrict__ pm, const float* __restrict__ tgt,
       float* __restrict__ A_part, float* __restrict__ D_part,
       float* __restrict__ Sp_part, int* __restrict__ StmI) {
    constexpr int CPX = NHW / SC;
    constexpr int KST = CPX / 16;
    int gid = blockIdx.x;
    int chunk = gid & (SC - 1);
    int b = gid / SC;
    int tid = threadIdx.x;
    int wv = tid >> 6, lane = tid & 63;
    int p0 = chunk * CPX;

    __shared__ uint32_t s_tb[CPX];
    __shared__ short s_bf[KST][512];
    __shared__ int cnt[NT];

    // ---- phase A: gather + tbits ----
    if (tid < CPX / 2) {
        // thread i covers dst pixels (p0+2i, p0+2i+1); src row 2*(p0>>8),
        // src cols 2*(p0&255)+4i .. +3 (float4; .x and .z are the even cols)
        const float* base = tgt + (((size_t)b * NT) * 512 + 2 * (p0 >> 8)) * 512
                                + 2 * (p0 & 255) + 4 * tid;
        uint32_t w0 = 0, w1 = 0;
#pragma unroll
        for (int t = 0; t < NT; ++t) {
            float4 v = *reinterpret_cast<const float4*>(base + (size_t)t * 512 * 512);
            w0 |= (v.x > 0.5f ? 1u : 0u) << t;
            w1 |= (v.z > 0.5f ? 1u : 0u) << t;
        }
        s_tb[2 * tid] = w0;
        s_tb[2 * tid + 1] = w1;
    }
    if (tid < NT) cnt[tid] = 0;
    __syncthreads();

    // ---- Stm popcount: one pixel word per thread (wave-uniform branch) ----
    if (tid < CPX) {
        uint32_t w = s_tb[tid];
#pragma unroll
        for (int t = 0; t < NT; ++t) {
            unsigned long long m = __ballot((w >> t) & 1u);
            if (lane == 0) atomicAdd(&cnt[t], (int)__popcll(m));
        }
    }

    // ---- phase B: build B-frags. lane l holds col=l&31, k = (l>>5)*8 + e ----
    for (int c = tid; c < KST * 64; c += 256) {
        int ls = c >> 6, l = c & 63;
        int col = l & 31;
        int kbase = ls * 16 + ((l >> 5) << 3);
        uint32_t pk[4];
#pragma unroll
        for (int e2 = 0; e2 < 4; ++e2) {
            uint32_t w0 = s_tb[kbase + 2 * e2];
            uint32_t w1 = s_tb[kbase + 2 * e2 + 1];
            uint32_t lo, hi;
            if (col < NT)       { lo = ((w0 >> col) & 1u) ? 0x3F80u : 0u;
                                  hi = ((w1 >> col) & 1u) ? 0x3F80u : 0u; }
            else if (col == NT) { lo = 0x3F80u; hi = 0x3F80u; }   // ones col
            else                { lo = 0u; hi = 0u; }
            pk[e2] = lo | (hi << 16);
        }
        *reinterpret_cast<uint4*>(&s_bf[ls][l * 8]) = *reinterpret_cast<const uint4*>(pk);
    }
    __syncthreads();
    if (tid < NT) atomicAdd(&StmI[b * NT + tid], cnt[tid]);

    // ---- phase C: K-loop ----
    int row = lane & 31;
    int q = wv * 32 + row;
    int qc = (q < NQ) ? q : 0;        // padded rows read row 0 (discarded)
    const float4* xp = reinterpret_cast<const float4*>(
        pm + ((size_t)(b * NQ + qc)) * NHW + p0 + ((lane >> 5) << 3));

    f32x16 accA, accD;
#pragma unroll
    for (int r = 0; r < 16; ++r) { accA[r] = 0.0f; accD[r] = 0.0f; }
    float mxsum = 0.0f, l2sum = 0.0f;
    const float LOG2E = 1.4426950408889634f;

#pragma unroll 2
    for (int s = 0; s < KST; ++s) {
        float4 xa = xp[s * 4];
        float4 xb4 = xp[s * 4 + 1];
        float xs[8] = {xa.x, xa.y, xa.z, xa.w, xb4.x, xb4.y, xb4.z, xb4.w};
        bf16x8 af, sf;
#pragma unroll
        for (int e = 0; e < 8; ++e) {
            float xi = xs[e];
            float y = xi * LOG2E;
            float e1 = fast_exp2(0.0f - fabsf(y));  // exp(-|x|)
            float tt = 1.0f + e1;
            float inv = __builtin_amdgcn_rcpf(tt);
            float sig = (xi >= 0.0f) ? inv : e1 * inv;
            l2sum += fast_log2(tt);                 // softplus = max(x,0)+ln2*log2(tt)
            mxsum += fmaxf(xi, 0.0f);
            af[e] = to_bf16(xi);
            sf[e] = to_bf16(sig);
        }
        bf16x8 bf = *reinterpret_cast<const bf16x8*>(&s_bf[s][lane * 8]);
        accA = __builtin_amdgcn_mfma_f32_32x32x16_bf16(af, bf, accA, 0, 0, 0);
        accD = __builtin_amdgcn_mfma_f32_32x32x16_bf16(sf, bf, accD, 0, 0, 0);
    }

    // Epilogue: C/D layout (verified): col = lane&31, row = (r&3)+8*(r>>2)+4*(lane>>5)
    int t = lane & 31;
#pragma unroll
    for (int r = 0; r < 16; ++r) {
        int rowD = (r & 3) + 8 * (r >> 2) + 4 * (lane >> 5);
        int qo = wv * 32 + rowD;
        if (qo < NQ && t <= NT) {
            size_t base = ((size_t)(chunk * NB + b) * NQ + qo) * (NT + 1) + t;
            A_part[base] = accA[r];
            D_part[base] = accD[r];
        }
    }
    float sp = fmaf(0.6931471805599453f, l2sum, mxsum);
    sp += __shfl_xor(sp, 32);
    if (lane < 32 && q < NQ)
        Sp_part[(size_t)(chunk * NB + b) * NQ + q] = sp;
}

// ---------------------------------------------------------------------------
// Kernel 2: assemble C[b,q,t]. One block (256 threads) per (b,q);
// wave w reduces chunks [w*SC/4, (w+1)*SC/4), LDS-combine, wave 0 epilogue.
// ---------------------------------------------------------------------------
template<int SC>
__global__ void __launch_bounds__(256)
k_assemble(const float* __restrict__ logits, const int* __restrict__ labels,
           const float* __restrict__ A_part, const float* __restrict__ D_part,
           const float* __restrict__ Sp_part, const int* __restrict__ StmI,
           float* __restrict__ Cout) {
    constexpr int CPW = SC / 4;        // chunks per wave
    int bq = blockIdx.x;
    int q = bq % NQ, b = bq / NQ;
    int tid = threadIdx.x, wv = tid >> 6, lane = tid & 63;
    __shared__ float sA[4][64], sD[4][64], sSn[4];

    float At = 0.0f, Dt = 0.0f;
    int t = lane;
    for (int cc = 0; cc < CPW; ++cc) {
        int c = wv * CPW + cc;
        size_t base = (size_t)(c * NB + b) * NQ + q;
        if (t <= NT) {
            At += A_part[base * (NT + 1) + t];
            Dt += D_part[base * (NT + 1) + t];
        }
    }
    {   // Sneg: lane-parallel over this wave's chunks
        float sp = 0.0f;
#pragma unroll
        for (int i = 0; i < CPW / 64; ++i) {
            int c = wv * CPW + i * 64 + lane;
            sp += Sp_part[(size_t)(c * NB + b) * NQ + q];
        }
        for (int o = 32; o; o >>= 1) sp += __shfl_xor(sp, o);
        if (lane == 0) sSn[wv] = sp;
    }
    sA[wv][lane] = At;
    sD[wv][lane] = Dt;
    __syncthreads();

    if (wv == 0) {
        float At4 = sA[0][lane] + sA[1][lane] + sA[2][lane] + sA[3][lane];
        float Dt4 = sD[0][lane] + sD[1][lane] + sD[2][lane] + sD[3][lane];
        float Sneg = sSn[0] + sSn[1] + sSn[2] + sSn[3];
        float Ssig = __shfl(Dt4, NT);                 // ones-column of D-GEMM

        const float* lg = logits + (size_t)bq * NCLS;
        float x0 = (lane < NCLS) ? lg[lane] : -INFINITY;
        float x1 = (lane + 64 < NCLS) ? lg[lane + 64] : -INFINITY;
        float mx = fmaxf(x0, x1);
        for (int o = 32; o; o >>= 1) mx = fmaxf(mx, __shfl_xor(mx, o));
        float s0 = (lane < NCLS) ? __expf(x0 - mx) : 0.0f;
        float s1 = (lane + 64 < NCLS) ? __expf(x1 - mx) : 0.0f;
        float sum = s0 + s1;
        for (int o = 32; o; o >>= 1) sum += __shfl_xor(sum, o);

        if (lane < NT) {
            int label = labels[b * NT + lane];
            float prob = __expf(lg[label] - mx) / sum;
            float cm = (Sneg - At4) * (1.0f / (float)NHW);
            float stm = (float)StmI[b * NT + lane];
            float cd = 1.0f - (2.0f * Dt4 + 1.0f) / (Ssig + stm + 1.0f);
            float c = 2.0f * (-prob) + 5.0f * cm + 5.0f * cd;
            if (isnan(c)) c = 0.0f;
            Cout[(size_t)bq * NT + lane] = c;
        }
    }
}

// ---------------------------------------------------------------------------
// Kernel 3: linear sum assignment (scipy shortest augmenting path, float64),
// on C[b].T (rows = targets 20, cols = queries 100). One wave per batch.
// ---------------------------------------------------------------------------
__global__ void __launch_bounds__(64)
k_lsa(const float* __restrict__ Cmat, float* __restrict__ out) {
    int b = blockIdx.x;
    int lane = threadIdx.x;
    __shared__ double cost[NT][NQ];
    __shared__ double u[NT], v[NQ], shortest[NQ];
    __shared__ int path[NQ], row4col[NQ], col4row[NT];
    __shared__ unsigned char SR[NT], SC[NQ];
    __shared__ int s_i, s_sink;
    __shared__ double s_minVal;
    __shared__ int qv[NT];

    for (int idx = lane; idx < NT * NQ; idx += 64) {
        int r = idx / NQ, j = idx % NQ;
        cost[r][j] = (double)Cmat[((size_t)b * NQ + j) * NT + r];
    }
    for (int j = lane; j < NQ; j += 64) { v[j] = 0.0; row4col[j] = -1; }
    if (lane < NT) { u[lane] = 0.0; col4row[lane] = -1; }
    __syncthreads();

    for (int cur = 0; cur < NT; ++cur) {
        for (int j = lane; j < NQ; j += 64) { shortest[j] = INFINITY; path[j] = -1; SC[j] = 0; }
        if (lane < NT) SR[lane] = 0;
        if (lane == 0) { s_i = cur; s_minVal = 0.0; s_sink = -1; }
        __syncthreads();

        while (true) {
            int i = s_i;
            double minVal = s_minVal;
            if (lane == 0) SR[i] = 1;
            double ui = u[i];
            double bestv = INFINITY;
            int bestj = NQ;
            for (int j = lane; j < NQ; j += 64) {
                if (!SC[j]) {
                    double d = minVal + cost[i][j] - ui - v[j];
                    if (d < shortest[j]) { shortest[j] = d; path[j] = i; }
                    double sj = shortest[j];
                    if (sj < bestv || (sj == bestv && j < bestj)) { bestv = sj; bestj = j; }
                }
            }
            for (int o = 32; o; o >>= 1) {
                double ov = __shfl_xor(bestv, o);
                int oj = __shfl_xor(bestj, o);
                if (ov < bestv || (ov == bestv && oj < bestj)) { bestv = ov; bestj = oj; }
            }
            __syncthreads();
            if (lane == 0) {
                SC[bestj] = 1;
                s_minVal = bestv;
                if (row4col[bestj] == -1) s_sink = bestj;
                else s_i = row4col[bestj];
            }
            __syncthreads();
            if (s_sink >= 0) break;
        }

        double minVal = s_minVal;
        int sink = s_sink;
        if (lane < NT) {
            if (lane == cur) u[lane] += minVal;
            else if (SR[lane]) u[lane] += minVal - shortest[col4row[lane]];
        }
        for (int j = lane; j < NQ; j += 64) {
            if (SC[j]) v[j] -= minVal - shortest[j];
        }
        __syncthreads();
        if (lane == 0) {
            int j = sink;
            while (true) {
                int i = path[j];
                row4col[j] = i;
                int nj = col4row[i];
                col4row[i] = j;
                j = nj;
                if (i == cur) break;
            }
        }
        __syncthreads();
    }

    if (lane < NT) qv[lane] = col4row[lane];
    __syncthreads();
    if (lane < NT) {
        int my = qv[lane];
        int rank = 0;
#pragma unroll
        for (int t2 = 0; t2 < NT; ++t2) rank += (qv[t2] < my) ? 1 : 0;
        out[NB * NQ * NT + b * NT + rank] = (float)my;              // pred_idx
        out[NB * NQ * NT + NB * NT + b * NT + rank] = (float)lane;  // tgt_idx
    }
}

// ---------------------------------------------------------------------------
extern "C" void kernel_launch(void* const* d_in, const int* in_sizes, int n_in,
                              void* d_out, int out_size, void* d_ws, size_t ws_size,
                              hipStream_t stream) {
    const float* pred_logits = (const float*)d_in[0];   // [4,100,81]
    const float* pred_masks  = (const float*)d_in[1];   // [4,100,256,256]
    const float* tgt_masks   = (const float*)d_in[2];   // [4,20,512,512]
    const int*   tgt_labels  = (const int*)d_in[3];     // [4,20]
    float* out = (float*)d_out;

    // partials footprint per SC: SC*NB*NQ*(21+21+1)*4 bytes (+ StmI)
    const size_t need512 = (size_t)512 * NB * NQ * 43 * 4 + 512;
    char* ws = (char*)d_ws;

    if (ws_size >= need512) {
        constexpr int SC = 512;
        float* A_part  = (float*)ws;
        float* D_part  = A_part + (size_t)SC * NB * NQ * (NT + 1);
        float* Sp_part = D_part + (size_t)SC * NB * NQ * (NT + 1);
        int*   StmI    = (int*)(Sp_part + (size_t)SC * NB * NQ);
        k_init<<<1, 128, 0, stream>>>(StmI);
        k_main<SC><<<NB * SC, 256, 0, stream>>>(pred_masks, tgt_masks, A_part, D_part,
                                                Sp_part, StmI);
        k_assemble<SC><<<NB * NQ, 256, 0, stream>>>(pred_logits, tgt_labels, A_part,
                                                    D_part, Sp_part, StmI, out);
    } else {
        constexpr int SC = 256;
        float* A_part  = (float*)ws;
        float* D_part  = A_part + (size_t)SC * NB * NQ * (NT + 1);
        float* Sp_part = D_part + (size_t)SC * NB * NQ * (NT + 1);
        int*   StmI    = (int*)(Sp_part + (size_t)SC * NB * NQ);
        k_init<<<1, 128, 0, stream>>>(StmI);
        k_main<SC><<<NB * SC, 256, 0, stream>>>(pred_masks, tgt_masks, A_part, D_part,
                                                Sp_part, StmI);
        k_assemble<SC><<<NB * NQ, 256, 0, stream>>>(pred_logits, tgt_labels, A_part,
                                                    D_part, Sp_part, StmI, out);
    }
    k_lsa<<<NB, 64, 0, stream>>>(out, out);
}

// Round 8
// 122.916 us; speedup vs baseline: 1.1576x; 1.1576x over previous
//
#include <hip/hip_runtime.h>
#include <hip/hip_bf16.h>
#include <math.h>
#include <stdint.h>

#define NB 4
#define NQ 100
#define NCLS 81
#define NT 20
#define NHW 65536

typedef __attribute__((ext_vector_type(8))) short bf16x8;
typedef __attribute__((ext_vector_type(16))) float f32x16;

__device__ inline short to_bf16(float f) {
    __hip_bfloat16 h = __float2bfloat16(f);   // RNE; pairs fuse to v_cvt_pk_bf16_f32
    return __builtin_bit_cast(short, h);
}

// v_exp_f32 / v_log_f32 are base-2 on gfx950
__device__ inline float fast_exp2(float x) { return __builtin_amdgcn_exp2f(x); }
__device__ inline float fast_log2(float x) { return __builtin_amdgcn_logf(x); }

// ---------------------------------------------------------------------------
// Kernel 0: zero the Stm integer accumulator (ws is poisoned, not re-poisoned)
// ---------------------------------------------------------------------------
__global__ void k_init(int* __restrict__ StmI) {
    if (threadIdx.x < NB * NT) StmI[threadIdx.x] = 0;
}

// ---------------------------------------------------------------------------
// Kernel 1: fused main pass. One block per (b, chunk of 256 pixels = row h).
//  phase A: threads 0..127 gather tgt (nearest 2x downsample) -> 20-bit
//           pixel words in LDS; ballot-popcount for Stm (int atomics).
//  phase B: build MFMA B-fragments (bf16 0/1; col 20 = all-ones -> Ssig free)
//  phase C: 4 waves x 32-q rows, 16 K-steps with a DEPTH-4 PREFETCH RING
//           (keeps >=4 K-steps of scattered row-loads in flight; the loads
//           are inherently 32-lines/instr since each lane owns a query row).
//           sigmoid/softplus VALU + two 32x32x16 bf16 MFMAs per K-step.
// ---------------------------------------------------------------------------
#define SC 256
#define CPX (NHW / SC)            // 256
#define KST (CPX / 16)            // 16
#define PF 4                      // prefetch depth (K-steps in flight)

__global__ void __launch_bounds__(256)
k_main(const float* __restrict__ pm, const float* __restrict__ tgt,
       float* __restrict__ A_part, float* __restrict__ D_part,
       float* __restrict__ Sp_part, int* __restrict__ StmI) {
    int gid = blockIdx.x;
    int chunk = gid & (SC - 1);           // == output row h
    int b = gid >> 8;
    int tid = threadIdx.x;
    int wv = tid >> 6, lane = tid & 63;
    int p0 = chunk * CPX;

    __shared__ uint32_t s_tb[CPX];        // 1 KB
    __shared__ short s_bf[KST][512];      // 16 KB B-fragments
    __shared__ int cnt[NT];

    // ---- phase A: gather + tbits ----
    if (tid < CPX / 2) {
        // thread i covers dst pixels (p0+2i, p0+2i+1); src row 2h, cols 4i..4i+3
        const float* base = tgt + (((size_t)b * NT) * 512 + 2 * chunk) * 512 + 4 * tid;
        uint32_t w0 = 0, w1 = 0;
#pragma unroll
        for (int t = 0; t < NT; ++t) {
            float4 v = *reinterpret_cast<const float4*>(base + (size_t)t * 512 * 512);
            w0 |= (v.x > 0.5f ? 1u : 0u) << t;
            w1 |= (v.z > 0.5f ? 1u : 0u) << t;
        }
        s_tb[2 * tid] = w0;
        s_tb[2 * tid + 1] = w1;
    }
    if (tid < NT) cnt[tid] = 0;
    __syncthreads();

    // ---- Stm popcount: one pixel word per thread ----
    {
        uint32_t w = s_tb[tid];
#pragma unroll
        for (int t = 0; t < NT; ++t) {
            unsigned long long m = __ballot((w >> t) & 1u);
            if (lane == 0) atomicAdd(&cnt[t], (int)__popcll(m));
        }
    }

    // ---- phase B: build B-frags. lane l holds col=l&31, k = (l>>5)*8 + e ----
    for (int c = tid; c < KST * 64; c += 256) {
        int ls = c >> 6, l = c & 63;
        int col = l & 31;
        int kbase = ls * 16 + ((l >> 5) << 3);
        uint32_t pk[4];
#pragma unroll
        for (int e2 = 0; e2 < 4; ++e2) {
            uint32_t w0 = s_tb[kbase + 2 * e2];
            uint32_t w1 = s_tb[kbase + 2 * e2 + 1];
            uint32_t lo, hi;
            if (col < NT)       { lo = ((w0 >> col) & 1u) ? 0x3F80u : 0u;
                                  hi = ((w1 >> col) & 1u) ? 0x3F80u : 0u; }
            else if (col == NT) { lo = 0x3F80u; hi = 0x3F80u; }   // ones col
            else                { lo = 0u; hi = 0u; }
            pk[e2] = lo | (hi << 16);
        }
        *reinterpret_cast<uint4*>(&s_bf[ls][l * 8]) = *reinterpret_cast<const uint4*>(pk);
    }
    __syncthreads();
    if (tid < NT) atomicAdd(&StmI[b * NT + tid], cnt[tid]);

    // ---- phase C: K-loop with depth-PF prefetch ring ----
    int row = lane & 31;
    int q = wv * 32 + row;
    int qc = (q < NQ) ? q : 0;        // padded rows read row 0 (discarded)
    const float4* xp = reinterpret_cast<const float4*>(
        pm + ((size_t)(b * NQ + qc)) * NHW + p0 + ((lane >> 5) << 3));

    f32x16 accA, accD;
#pragma unroll
    for (int r = 0; r < 16; ++r) { accA[r] = 0.0f; accD[r] = 0.0f; }
    float mxsum = 0.0f, l2sum = 0.0f;
    const float LOG2E = 1.4426950408889634f;

    float4 b0[PF], b1[PF];
#pragma unroll
    for (int i = 0; i < PF; ++i) { b0[i] = xp[i * 4]; b1[i] = xp[i * 4 + 1]; }

#pragma unroll
    for (int s = 0; s < KST; ++s) {
        float4 xa = b0[s & (PF - 1)];
        float4 xb4 = b1[s & (PF - 1)];
        if (s + PF < KST) {             // refill ring (static indices, full unroll)
            b0[s & (PF - 1)] = xp[(s + PF) * 4];
            b1[s & (PF - 1)] = xp[(s + PF) * 4 + 1];
        }
        float xs[8] = {xa.x, xa.y, xa.z, xa.w, xb4.x, xb4.y, xb4.z, xb4.w};
        bf16x8 af, sf;
#pragma unroll
        for (int e = 0; e < 8; ++e) {
            float xi = xs[e];
            float y = xi * LOG2E;
            float e1 = fast_exp2(0.0f - fabsf(y));  // exp(-|x|)
            float tt = 1.0f + e1;
            float inv = __builtin_amdgcn_rcpf(tt);
            float sig = (xi >= 0.0f) ? inv : e1 * inv;
            l2sum += fast_log2(tt);                 // softplus = max(x,0)+ln2*log2(tt)
            mxsum += fmaxf(xi, 0.0f);
            af[e] = to_bf16(xi);
            sf[e] = to_bf16(sig);
        }
        bf16x8 bf = *reinterpret_cast<const bf16x8*>(&s_bf[s][lane * 8]);
        accA = __builtin_amdgcn_mfma_f32_32x32x16_bf16(af, bf, accA, 0, 0, 0);
        accD = __builtin_amdgcn_mfma_f32_32x32x16_bf16(sf, bf, accD, 0, 0, 0);
    }

    // Epilogue: C/D layout (verified): col = lane&31, row = (r&3)+8*(r>>2)+4*(lane>>5)
    int t = lane & 31;
#pragma unroll
    for (int r = 0; r < 16; ++r) {
        int rowD = (r & 3) + 8 * (r >> 2) + 4 * (lane >> 5);
        int qo = wv * 32 + rowD;
        if (qo < NQ && t <= NT) {
            size_t base = ((size_t)(chunk * NB + b) * NQ + qo) * (NT + 1) + t;
            A_part[base] = accA[r];
            D_part[base] = accD[r];
        }
    }
    float sp = fmaf(0.6931471805599453f, l2sum, mxsum);
    sp += __shfl_xor(sp, 32);
    if (lane < 32 && q < NQ)
        Sp_part[(size_t)(chunk * NB + b) * NQ + q] = sp;
}

// ---------------------------------------------------------------------------
// Kernel 2: assemble C[b,q,t]. One block (256 threads) per (b,q);
// wave w reduces chunks [w*64, w*64+64), LDS-combine, wave 0 epilogue.
// ---------------------------------------------------------------------------
__global__ void __launch_bounds__(256)
k_assemble(const float* __restrict__ logits, const int* __restrict__ labels,
           const float* __restrict__ A_part, const float* __restrict__ D_part,
           const float* __restrict__ Sp_part, const int* __restrict__ StmI,
           float* __restrict__ Cout) {
    constexpr int CPW = SC / 4;        // 64 chunks per wave
    int bq = blockIdx.x;
    int q = bq % NQ, b = bq / NQ;
    int tid = threadIdx.x, wv = tid >> 6, lane = tid & 63;
    __shared__ float sA[4][64], sD[4][64], sSn[4];

    float At = 0.0f, Dt = 0.0f;
    int t = lane;
    for (int cc = 0; cc < CPW; ++cc) {
        int c = wv * CPW + cc;
        size_t base = (size_t)(c * NB + b) * NQ + q;
        if (t <= NT) {
            At += A_part[base * (NT + 1) + t];
            Dt += D_part[base * (NT + 1) + t];
        }
    }
    {   // Sneg: lane-parallel over this wave's chunks
        int c = wv * CPW + lane;
        float sp = Sp_part[(size_t)(c * NB + b) * NQ + q];
        for (int o = 32; o; o >>= 1) sp += __shfl_xor(sp, o);
        if (lane == 0) sSn[wv] = sp;
    }
    sA[wv][lane] = At;
    sD[wv][lane] = Dt;
    __syncthreads();

    if (wv == 0) {
        float At4 = sA[0][lane] + sA[1][lane] + sA[2][lane] + sA[3][lane];
        float Dt4 = sD[0][lane] + sD[1][lane] + sD[2][lane] + sD[3][lane];
        float Sneg = sSn[0] + sSn[1] + sSn[2] + sSn[3];
        float Ssig = __shfl(Dt4, NT);                 // ones-column of D-GEMM

        const float* lg = logits + (size_t)bq * NCLS;
        float x0 = (lane < NCLS) ? lg[lane] : -INFINITY;
        float x1 = (lane + 64 < NCLS) ? lg[lane + 64] : -INFINITY;
        float mx = fmaxf(x0, x1);
        for (int o = 32; o; o >>= 1) mx = fmaxf(mx, __shfl_xor(mx, o));
        float s0 = (lane < NCLS) ? __expf(x0 - mx) : 0.0f;
        float s1 = (lane + 64 < NCLS) ? __expf(x1 - mx) : 0.0f;
        float sum = s0 + s1;
        for (int o = 32; o; o >>= 1) sum += __shfl_xor(sum, o);

        if (lane < NT) {
            int label = labels[b * NT + lane];
            float prob = __expf(lg[label] - mx) / sum;
            float cm = (Sneg - At4) * (1.0f / (float)NHW);
            float stm = (float)StmI[b * NT + lane];
            float cd = 1.0f - (2.0f * Dt4 + 1.0f) / (Ssig + stm + 1.0f);
            float c = 2.0f * (-prob) + 5.0f * cm + 5.0f * cd;
            if (isnan(c)) c = 0.0f;
            Cout[(size_t)bq * NT + lane] = c;
        }
    }
}

// ---------------------------------------------------------------------------
// Kernel 3: linear sum assignment (scipy shortest augmenting path, float64),
// on C[b].T (rows = targets 20, cols = queries 100). One wave per batch.
// ---------------------------------------------------------------------------
__global__ void __launch_bounds__(64)
k_lsa(const float* __restrict__ Cmat, float* __restrict__ out) {
    int b = blockIdx.x;
    int lane = threadIdx.x;
    __shared__ double cost[NT][NQ];
    __shared__ double u[NT], v[NQ], shortest[NQ];
    __shared__ int path[NQ], row4col[NQ], col4row[NT];
    __shared__ unsigned char SR[NT], SCm[NQ];
    __shared__ int s_i, s_sink;
    __shared__ double s_minVal;
    __shared__ int qv[NT];

    for (int idx = lane; idx < NT * NQ; idx += 64) {
        int r = idx / NQ, j = idx % NQ;
        cost[r][j] = (double)Cmat[((size_t)b * NQ + j) * NT + r];
    }
    for (int j = lane; j < NQ; j += 64) { v[j] = 0.0; row4col[j] = -1; }
    if (lane < NT) { u[lane] = 0.0; col4row[lane] = -1; }
    __syncthreads();

    for (int cur = 0; cur < NT; ++cur) {
        for (int j = lane; j < NQ; j += 64) { shortest[j] = INFINITY; path[j] = -1; SCm[j] = 0; }
        if (lane < NT) SR[lane] = 0;
        if (lane == 0) { s_i = cur; s_minVal = 0.0; s_sink = -1; }
        __syncthreads();

        while (true) {
            int i = s_i;
            double minVal = s_minVal;
            if (lane == 0) SR[i] = 1;
            double ui = u[i];
            double bestv = INFINITY;
            int bestj = NQ;
            for (int j = lane; j < NQ; j += 64) {
                if (!SCm[j]) {
                    double d = minVal + cost[i][j] - ui - v[j];
                    if (d < shortest[j]) { shortest[j] = d; path[j] = i; }
                    double sj = shortest[j];
                    if (sj < bestv || (sj == bestv && j < bestj)) { bestv = sj; bestj = j; }
                }
            }
            for (int o = 32; o; o >>= 1) {
                double ov = __shfl_xor(bestv, o);
                int oj = __shfl_xor(bestj, o);
                if (ov < bestv || (ov == bestv && oj < bestj)) { bestv = ov; bestj = oj; }
            }
            __syncthreads();
            if (lane == 0) {
                SCm[bestj] = 1;
                s_minVal = bestv;
                if (row4col[bestj] == -1) s_sink = bestj;
                else s_i = row4col[bestj];
            }
            __syncthreads();
            if (s_sink >= 0) break;
        }

        double minVal = s_minVal;
        int sink = s_sink;
        if (lane < NT) {
            if (lane == cur) u[lane] += minVal;
            else if (SR[lane]) u[lane] += minVal - shortest[col4row[lane]];
        }
        for (int j = lane; j < NQ; j += 64) {
            if (SCm[j]) v[j] -= minVal - shortest[j];
        }
        __syncthreads();
        if (lane == 0) {
            int j = sink;
            while (true) {
                int i = path[j];
                row4col[j] = i;
                int nj = col4row[i];
                col4row[i] = j;
                j = nj;
                if (i == cur) break;
            }
        }
        __syncthreads();
    }

    if (lane < NT) qv[lane] = col4row[lane];
    __syncthreads();
    if (lane < NT) {
        int my = qv[lane];
        int rank = 0;
#pragma unroll
        for (int t2 = 0; t2 < NT; ++t2) rank += (qv[t2] < my) ? 1 : 0;
        out[NB * NQ * NT + b * NT + rank] = (float)my;              // pred_idx
        out[NB * NQ * NT + NB * NT + b * NT + rank] = (float)lane;  // tgt_idx
    }
}

// ---------------------------------------------------------------------------
extern "C" void kernel_launch(void* const* d_in, const int* in_sizes, int n_in,
                              void* d_out, int out_size, void* d_ws, size_t ws_size,
                              hipStream_t stream) {
    const float* pred_logits = (const float*)d_in[0];   // [4,100,81]
    const float* pred_masks  = (const float*)d_in[1];   // [4,100,256,256]
    const float* tgt_masks   = (const float*)d_in[2];   // [4,20,512,512]
    const int*   tgt_labels  = (const int*)d_in[3];     // [4,20]
    float* out = (float*)d_out;

    char* ws = (char*)d_ws;
    float* A_part  = (float*)ws;                                      // SC*NB*NQ*21
    float* D_part  = A_part + (size_t)SC * NB * NQ * (NT + 1);
    float* Sp_part = D_part + (size_t)SC * NB * NQ * (NT + 1);        // SC*NB*NQ
    int*   StmI    = (int*)(Sp_part + (size_t)SC * NB * NQ);          // NB*NT ints

    k_init<<<1, 128, 0, stream>>>(StmI);
    k_main<<<NB * SC, 256, 0, stream>>>(pred_masks, tgt_masks, A_part, D_part,
                                        Sp_part, StmI);
    k_assemble<<<NB * NQ, 256, 0, stream>>>(pred_logits, tgt_labels, A_part, D_part,
                                            Sp_part, StmI, out);
    k_lsa<<<NB, 64, 0, stream>>>(out, out);
}

// Round 9
// 110.550 us; speedup vs baseline: 1.2871x; 1.1119x over previous
//
#include <hip/hip_runtime.h>
#include <hip/hip_bf16.h>
#include <math.h>
#include <stdint.h>

#define NB 4
#define NQ 100
#define NQR 101                   // partial rows: 100 queries + ones-row (Stm)
#define NCLS 81
#define NT 20
#define NHW 65536

#define SC 256                    // split-K chunks: one 256-px output row each
#define CPX (NHW / SC)            // 256
#define KST (CPX / 16)            // 16 MFMA K-steps

typedef __attribute__((ext_vector_type(8))) short bf16x8;
typedef __attribute__((ext_vector_type(16))) float f32x16;

__device__ inline short to_bf16(float f) {
    __hip_bfloat16 h = __float2bfloat16(f);   // RNE; pairs fuse to v_cvt_pk_bf16_f32
    return __builtin_bit_cast(short, h);
}

// v_exp_f32 / v_log_f32 are base-2 on gfx950
__device__ inline float fast_exp2(float x) { return __builtin_amdgcn_exp2f(x); }
__device__ inline float fast_log2(float x) { return __builtin_amdgcn_logf(x); }

// ---------------------------------------------------------------------------
// Kernel 1: fused main pass. One block per (b, output row h = chunk).
//  phase A: threads 0..127 gather tgt (nearest 2x downsample) -> 20-bit words
//  phase B: build MFMA B-fragments (bf16 0/1; col 20 = all-ones -> Ssig free)
//  phase C: 4 waves x 32-q rows, two 32x32x16 bf16 MFMAs per K-step
//           (x-GEMM -> A, sig-GEMM -> D). Padded query row 100 carries an
//           all-ones A-fragment, so A[100][t] = per-chunk popcount(tm_t)
//           (exact in fp32) -> Stm without atomics or an init kernel.
// ---------------------------------------------------------------------------
__global__ void __launch_bounds__(256)
k_main(const float* __restrict__ pm, const float* __restrict__ tgt,
       float* __restrict__ A_part, float* __restrict__ D_part,
       float* __restrict__ Sp_part) {
    int gid = blockIdx.x;
    int chunk = gid & (SC - 1);           // == output row h
    int b = gid >> 8;
    int tid = threadIdx.x;
    int wv = tid >> 6, lane = tid & 63;
    int p0 = chunk * CPX;

    __shared__ uint32_t s_tb[CPX];        // 1 KB
    __shared__ short s_bf[KST][512];      // 16 KB B-fragments

    // ---- phase A: gather + tbits ----
    if (tid < CPX / 2) {
        // thread i covers dst pixels (p0+2i, p0+2i+1); src row 2h, cols 4i..4i+3
        const float* base = tgt + (((size_t)b * NT) * 512 + 2 * chunk) * 512 + 4 * tid;
        uint32_t w0 = 0, w1 = 0;
#pragma unroll
        for (int t = 0; t < NT; ++t) {
            float4 v = *reinterpret_cast<const float4*>(base + (size_t)t * 512 * 512);
            w0 |= (v.x > 0.5f ? 1u : 0u) << t;
            w1 |= (v.z > 0.5f ? 1u : 0u) << t;
        }
        s_tb[2 * tid] = w0;
        s_tb[2 * tid + 1] = w1;
    }
    __syncthreads();

    // ---- phase B: build B-frags. lane l holds col=l&31, k = (l>>5)*8 + e ----
    for (int c = tid; c < KST * 64; c += 256) {
        int ls = c >> 6, l = c & 63;
        int col = l & 31;
        int kbase = ls * 16 + ((l >> 5) << 3);
        uint32_t pk[4];
#pragma unroll
        for (int e2 = 0; e2 < 4; ++e2) {
            uint32_t w0 = s_tb[kbase + 2 * e2];
            uint32_t w1 = s_tb[kbase + 2 * e2 + 1];
            uint32_t lo, hi;
            if (col < NT)       { lo = ((w0 >> col) & 1u) ? 0x3F80u : 0u;
                                  hi = ((w1 >> col) & 1u) ? 0x3F80u : 0u; }
            else if (col == NT) { lo = 0x3F80u; hi = 0x3F80u; }   // ones col
            else                { lo = 0u; hi = 0u; }
            pk[e2] = lo | (hi << 16);
        }
        *reinterpret_cast<uint4*>(&s_bf[ls][l * 8]) = *reinterpret_cast<const uint4*>(pk);
    }
    __syncthreads();

    // ---- phase C: K-loop ----
    int row = lane & 31;
    int q = wv * 32 + row;
    int qc = (q < NQ) ? q : 0;        // padded rows read row 0 (discarded)
    const float4* xp = reinterpret_cast<const float4*>(
        pm + ((size_t)(b * NQ + qc)) * NHW + p0 + ((lane >> 5) << 3));

    f32x16 accA, accD;
#pragma unroll
    for (int r = 0; r < 16; ++r) { accA[r] = 0.0f; accD[r] = 0.0f; }
    float mxsum = 0.0f, l2sum = 0.0f;
    const float LOG2E = 1.4426950408889634f;
    const bool ones_row = (q == NQ);  // query row 100: A-frag = all ones
    bf16x8 ones;
#pragma unroll
    for (int e = 0; e < 8; ++e) ones[e] = (short)0x3F80;

#pragma unroll 4
    for (int s = 0; s < KST; ++s) {
        float4 xa = xp[s * 4];
        float4 xb4 = xp[s * 4 + 1];
        float xs[8] = {xa.x, xa.y, xa.z, xa.w, xb4.x, xb4.y, xb4.z, xb4.w};
        bf16x8 af, sf;
#pragma unroll
        for (int e = 0; e < 8; ++e) {
            float xi = xs[e];
            float y = xi * LOG2E;
            float e1 = fast_exp2(0.0f - fabsf(y));  // exp(-|x|)
            float tt = 1.0f + e1;
            float inv = __builtin_amdgcn_rcpf(tt);
            float sig = (xi >= 0.0f) ? inv : e1 * inv;
            l2sum += fast_log2(tt);                 // softplus = max(x,0)+ln2*log2(tt)
            mxsum += fmaxf(xi, 0.0f);
            af[e] = to_bf16(xi);
            sf[e] = to_bf16(sig);
        }
        if (ones_row) af = ones;
        bf16x8 bf = *reinterpret_cast<const bf16x8*>(&s_bf[s][lane * 8]);
        accA = __builtin_amdgcn_mfma_f32_32x32x16_bf16(af, bf, accA, 0, 0, 0);
        accD = __builtin_amdgcn_mfma_f32_32x32x16_bf16(sf, bf, accD, 0, 0, 0);
    }

    // Epilogue: C/D layout (verified): col = lane&31, row = (r&3)+8*(r>>2)+4*(lane>>5)
    int t = lane & 31;
#pragma unroll
    for (int r = 0; r < 16; ++r) {
        int rowD = (r & 3) + 8 * (r >> 2) + 4 * (lane >> 5);
        int qo = wv * 32 + rowD;
        if (qo <= NQ && t <= NT) {      // qo==100 is the ones/Stm row
            size_t base = ((size_t)(chunk * NB + b) * NQR + qo) * (NT + 1) + t;
            A_part[base] = accA[r];
            D_part[base] = accD[r];
        }
    }
    float sp = fmaf(0.6931471805599453f, l2sum, mxsum);
    sp += __shfl_xor(sp, 32);
    if (lane < 32 && q < NQ)
        Sp_part[(size_t)(chunk * NB + b) * NQ + q] = sp;
}

// ---------------------------------------------------------------------------
// Kernel 2: assemble C[b,q,t]. One block (256 threads) per (b,q);
// wave w reduces chunks [w*64, w*64+64) (incl. Stm row 100), LDS-combine,
// wave 0 does softmax + epilogue.
// ---------------------------------------------------------------------------
__global__ void __launch_bounds__(256)
k_assemble(const float* __restrict__ logits, const int* __restrict__ labels,
           const float* __restrict__ A_part, const float* __restrict__ D_part,
           const float* __restrict__ Sp_part, float* __restrict__ Cout) {
    constexpr int CPW = SC / 4;        // 64 chunks per wave
    int bq = blockIdx.x;
    int q = bq % NQ, b = bq / NQ;
    int tid = threadIdx.x, wv = tid >> 6, lane = tid & 63;
    __shared__ float sA[4][64], sD[4][64], sS[4][64], sSn[4];

    float At = 0.0f, Dt = 0.0f, St = 0.0f;
    int t = lane;
    for (int cc = 0; cc < CPW; ++cc) {
        int c = wv * CPW + cc;
        size_t cb = (size_t)(c * NB + b) * NQR;
        if (t <= NT) {
            At += A_part[(cb + q) * (NT + 1) + t];
            Dt += D_part[(cb + q) * (NT + 1) + t];
            St += A_part[(cb + NQ) * (NT + 1) + t];   // ones-row -> Stm
        }
    }
    {   // Sneg: lane-parallel over this wave's chunks
        int c = wv * CPW + lane;
        float sp = Sp_part[(size_t)(c * NB + b) * NQ + q];
        for (int o = 32; o; o >>= 1) sp += __shfl_xor(sp, o);
        if (lane == 0) sSn[wv] = sp;
    }
    sA[wv][lane] = At;
    sD[wv][lane] = Dt;
    sS[wv][lane] = St;
    __syncthreads();

    if (wv == 0) {
        float At4 = sA[0][lane] + sA[1][lane] + sA[2][lane] + sA[3][lane];
        float Dt4 = sD[0][lane] + sD[1][lane] + sD[2][lane] + sD[3][lane];
        float St4 = sS[0][lane] + sS[1][lane] + sS[2][lane] + sS[3][lane];
        float Sneg = sSn[0] + sSn[1] + sSn[2] + sSn[3];
        float Ssig = __shfl(Dt4, NT);                 // ones-column of D-GEMM

        const float* lg = logits + (size_t)bq * NCLS;
        float x0 = (lane < NCLS) ? lg[lane] : -INFINITY;
        float x1 = (lane + 64 < NCLS) ? lg[lane + 64] : -INFINITY;
        float mx = fmaxf(x0, x1);
        for (int o = 32; o; o >>= 1) mx = fmaxf(mx, __shfl_xor(mx, o));
        float s0 = (lane < NCLS) ? __expf(x0 - mx) : 0.0f;
        float s1 = (lane + 64 < NCLS) ? __expf(x1 - mx) : 0.0f;
        float sum = s0 + s1;
        for (int o = 32; o; o >>= 1) sum += __shfl_xor(sum, o);

        if (lane < NT) {
            int label = labels[b * NT + lane];
            float prob = __expf(lg[label] - mx) / sum;
            float cm = (Sneg - At4) * (1.0f / (float)NHW);
            float cd = 1.0f - (2.0f * Dt4 + 1.0f) / (Ssig + St4 + 1.0f);
            float c = 2.0f * (-prob) + 5.0f * cm + 5.0f * cd;
            if (isnan(c)) c = 0.0f;
            Cout[(size_t)bq * NT + lane] = c;
        }
    }
}

// ---------------------------------------------------------------------------
// Kernel 3: linear sum assignment (scipy shortest augmenting path, float64),
// on C[b].T (rows = targets 20, cols = queries 100). One wave per batch.
// ---------------------------------------------------------------------------
__global__ void __launch_bounds__(64)
k_lsa(const float* __restrict__ Cmat, float* __restrict__ out) {
    int b = blockIdx.x;
    int lane = threadIdx.x;
    __shared__ double cost[NT][NQ];
    __shared__ double u[NT], v[NQ], shortest[NQ];
    __shared__ int path[NQ], row4col[NQ], col4row[NT];
    __shared__ unsigned char SR[NT], SCm[NQ];
    __shared__ int s_i, s_sink;
    __shared__ double s_minVal;
    __shared__ int qv[NT];

    for (int idx = lane; idx < NT * NQ; idx += 64) {
        int r = idx / NQ, j = idx % NQ;
        cost[r][j] = (double)Cmat[((size_t)b * NQ + j) * NT + r];
    }
    for (int j = lane; j < NQ; j += 64) { v[j] = 0.0; row4col[j] = -1; }
    if (lane < NT) { u[lane] = 0.0; col4row[lane] = -1; }
    __syncthreads();

    for (int cur = 0; cur < NT; ++cur) {
        for (int j = lane; j < NQ; j += 64) { shortest[j] = INFINITY; path[j] = -1; SCm[j] = 0; }
        if (lane < NT) SR[lane] = 0;
        if (lane == 0) { s_i = cur; s_minVal = 0.0; s_sink = -1; }
        __syncthreads();

        while (true) {
            int i = s_i;
            double minVal = s_minVal;
            if (lane == 0) SR[i] = 1;
            double ui = u[i];
            double bestv = INFINITY;
            int bestj = NQ;
            for (int j = lane; j < NQ; j += 64) {
                if (!SCm[j]) {
                    double d = minVal + cost[i][j] - ui - v[j];
                    if (d < shortest[j]) { shortest[j] = d; path[j] = i; }
                    double sj = shortest[j];
                    if (sj < bestv || (sj == bestv && j < bestj)) { bestv = sj; bestj = j; }
                }
            }
            for (int o = 32; o; o >>= 1) {
                double ov = __shfl_xor(bestv, o);
                int oj = __shfl_xor(bestj, o);
                if (ov < bestv || (ov == bestv && oj < bestj)) { bestv = ov; bestj = oj; }
            }
            __syncthreads();
            if (lane == 0) {
                SCm[bestj] = 1;
                s_minVal = bestv;
                if (row4col[bestj] == -1) s_sink = bestj;
                else s_i = row4col[bestj];
            }
            __syncthreads();
            if (s_sink >= 0) break;
        }

        double minVal = s_minVal;
        int sink = s_sink;
        if (lane < NT) {
            if (lane == cur) u[lane] += minVal;
            else if (SR[lane]) u[lane] += minVal - shortest[col4row[lane]];
        }
        for (int j = lane; j < NQ; j += 64) {
            if (SCm[j]) v[j] -= minVal - shortest[j];
        }
        __syncthreads();
        if (lane == 0) {
            int j = sink;
            while (true) {
                int i = path[j];
                row4col[j] = i;
                int nj = col4row[i];
                col4row[i] = j;
                j = nj;
                if (i == cur) break;
            }
        }
        __syncthreads();
    }

    if (lane < NT) qv[lane] = col4row[lane];
    __syncthreads();
    if (lane < NT) {
        int my = qv[lane];
        int rank = 0;
#pragma unroll
        for (int t2 = 0; t2 < NT; ++t2) rank += (qv[t2] < my) ? 1 : 0;
        out[NB * NQ * NT + b * NT + rank] = (float)my;              // pred_idx
        out[NB * NQ * NT + NB * NT + b * NT + rank] = (float)lane;  // tgt_idx
    }
}

// ---------------------------------------------------------------------------
extern "C" void kernel_launch(void* const* d_in, const int* in_sizes, int n_in,
                              void* d_out, int out_size, void* d_ws, size_t ws_size,
                              hipStream_t stream) {
    const float* pred_logits = (const float*)d_in[0];   // [4,100,81]
    const float* pred_masks  = (const float*)d_in[1];   // [4,100,256,256]
    const float* tgt_masks   = (const float*)d_in[2];   // [4,20,512,512]
    const int*   tgt_labels  = (const int*)d_in[3];     // [4,20]
    float* out = (float*)d_out;

    char* ws = (char*)d_ws;
    float* A_part  = (float*)ws;                                      // SC*NB*NQR*21
    float* D_part  = A_part + (size_t)SC * NB * NQR * (NT + 1);
    float* Sp_part = D_part + (size_t)SC * NB * NQR * (NT + 1);       // SC*NB*NQ

    k_main<<<NB * SC, 256, 0, stream>>>(pred_masks, tgt_masks, A_part, D_part, Sp_part);
    k_assemble<<<NB * NQ, 256, 0, stream>>>(pred_logits, tgt_labels, A_part, D_part,
                                            Sp_part, out);
    k_lsa<<<NB, 64, 0, stream>>>(out, out);
}